// Round 10
// baseline (571.821 us; speedup 1.0000x reference)
//
#include <hip/hip_runtime.h>
#include <hip/hip_bf16.h>
#include <hip/hip_cooperative_groups.h>
#include <math.h>

namespace cg = cooperative_groups;
typedef __hip_bfloat16 bf16;

// ---------------- problem constants ----------------
#define LSEQ 4096
#define DI 128
#define NSTATE 16
#define NK 4
#define NCHUNK 128
#define CLEN 32
#define CHTOT 16384   // 2 scans * 4 k * 128 d * 16 n
#define NBLK 256      // cooperative grid: 256 blocks x 256 threads (always co-resident)

// ---------------- fp32 input staging ----------------
#define IN_X0    0
#define IN_X1    262144
#define IN_IPW0  524288
#define IN_IPW1  540672
#define IN_CW0   557056
#define IN_CB0   558208
#define IN_CW1   558336
#define IN_CB1   559488
#define IN_XPW0  559616
#define IN_DTW0  578048
#define IN_DTW1  580096
#define IN_DTB0  582144
#define IN_DTB1  582656
#define IN_AL0   583168
#define IN_AL1   591360
#define IN_DS0   599552
#define IN_DS1   600064
#define IN_G0    600576
#define IN_B0    600704
#define IN_G1    600832
#define IN_B1    600960
#define IN_WO0   601088
#define IN_WO1   609280
#define END_IN   617472

// ---------------- intermediate buffers ----------------
#define OFF_XC0  END_IN
#define OFF_XC1  (OFF_XC0 + DI*LSEQ)
#define OFF_XT0  (OFF_XC1 + DI*LSEQ)
#define OFF_XT1  (OFF_XT0 + DI*LSEQ)
#define OFF_SZ0  (OFF_XT1 + DI*LSEQ)
#define OFF_SZ1  (OFF_SZ0 + LSEQ*DI)
#define OFF_XDBL (OFF_SZ1 + LSEQ*DI)
#define OFF_CHP  (OFF_XDBL + NK*36*LSEQ)
#define OFF_CHS  (OFF_CHP + NCHUNK*CHTOT)
#define OFF_OY   (OFF_CHS + NCHUNK*CHTOT)
#define WS_FLOATS (OFF_OY + 2*NK*LSEQ*DI)

#define SA_HALF 4608   // scanA per-half smem floats: us 4224 + dtr 64 + Bt 320
#define SB_HALF 4928   // scanB: + Ct 320
#define SMEM_FLOATS 10368

__device__ __forceinline__ float softplus_f(float x) {
  return x > 20.f ? x : __logf(1.f + __expf(x));
}
__device__ __forceinline__ float silu_f(float x) {
  return x / (1.f + __expf(-x));
}
__device__ __forceinline__ int probe_f32(const void* probe, int t, int* sh) {
  if (t < 64) {
    int idx = 2 * ((t * 127) & 4095);
    float v = __bfloat162float(((const bf16*)probe)[idx]);
    int weird = (!(v == v)) || (fabsf(v) > 4.0f);
    unsigned long long m = __ballot(weird);
    if (t == 0) *sh = (__popcll(m) >= 8) ? 1 : 0;
  }
  __syncthreads();
  return *sh;
}

struct Ptrs { const void* p[23]; };
__constant__ const int g_cnt[23] = {262144, 262144, 16384, 16384, 1152, 128, 1152, 128,
                                    18432, 2048, 2048, 512, 512, 8192, 8192, 512, 512,
                                    128, 128, 128, 128, 8192, 8192};
__constant__ const int g_dst[23] = {IN_X0, IN_X1, IN_IPW0, IN_IPW1, IN_CW0, IN_CB0,
                                    IN_CW1, IN_CB1, IN_XPW0, IN_DTW0, IN_DTW1, IN_DTB0,
                                    IN_DTB1, IN_AL0, IN_AL1, IN_DS0, IN_DS1, IN_G0,
                                    IN_B0, IN_G1, IN_B1, IN_WO0, IN_WO1};

// ================= phase bodies (shared by mega + discrete) =================

__device__ __forceinline__ void ph_convert(const Ptrs& pt, int f32, float* __restrict__ ws,
                                           int gid0, int stride) {
  for (int gid = gid0; gid < END_IN; gid += stride) {
    int j = 0;
#pragma unroll
    for (int q = 0; q < 22; q++)
      if (gid >= g_dst[q] + g_cnt[q]) j = q + 1;
    int off = gid - g_dst[j];
    float v;
    if (f32) v = ((const float*)pt.p[j])[off];
    else v = __bfloat162float(((const bf16*)pt.p[j])[off]);
    ws[gid] = v;
  }
}

// unit: 0..511 (b = unit>>8, l0 = (unit&255)*16). smem: 2176 floats.
__device__ __forceinline__ void ph_inproj(float* __restrict__ ws, float* sm, int t, int unit) {
  int b = unit >> 8;
  int l0 = (unit & 255) * 16;
  const float* __restrict__ x = ws + (b ? IN_X1 : IN_X0);
  const float* __restrict__ w = ws + (b ? IN_IPW1 : IN_IPW0);
  float* xi = ws + (b ? OFF_XC1 : OFF_XC0);
  float* sz = ws + (b ? OFF_SZ1 : OFF_SZ0);
  int j = t;  // output channel
  float4 wr[16];
#pragma unroll
  for (int q = 0; q < 16; q++) wr[q] = *(const float4*)&w[j * 64 + 4 * q];
  float acc[16];
#pragma unroll
  for (int p = 0; p < 16; p++) acc[p] = 0.f;
#pragma unroll 4
  for (int p = 0; p < 16; p++) {
    const float* xr = x + (l0 + p) * 64;  // block-uniform -> s_load
#pragma unroll
    for (int q = 0; q < 16; q++) {
      float4 x4 = *(const float4*)&xr[4 * q];
      acc[p] += x4.x * wr[q].x + x4.y * wr[q].y + x4.z * wr[q].z + x4.w * wr[q].w;
    }
  }
  if (j < 128) {
#pragma unroll
    for (int p = 0; p < 16; p++) sm[j * 17 + p] = acc[p];
  } else {
    int d = j - 128;
#pragma unroll
    for (int p = 0; p < 16; p++) sz[(l0 + p) * 128 + d] = silu_f(acc[p]);
  }
  __syncthreads();
#pragma unroll
  for (int r8 = 0; r8 < 8; r8++) {
    int row = (t >> 4) + 16 * r8, col = t & 15;
    xi[row * LSEQ + l0 + col] = sm[row * 17 + col];  // 16-consec stores
  }
}

// unit: 0..255 (b = unit>>7, d = unit&127). smem: 8256 floats.
__device__ __forceinline__ void ph_conv(float* __restrict__ ws, float* sm, int t, int unit) {
  int b = unit >> 7, d = unit & 127;
  const float* cw = ws + (b ? IN_CW1 : IN_CW0) + d * 9;
  float bias = (ws + (b ? IN_CB1 : IN_CB0))[d];
  float* xp = ws + (b ? OFF_XC1 : OFF_XC0) + d * LSEQ;
  float* xt = ws + (b ? OFF_XT1 : OFF_XT0) + d * LSEQ;
  float wreg[9];
#pragma unroll
  for (int i = 0; i < 9; i++) wreg[i] = cw[i];
  float* pl = sm;         // [64][64]
  float* po = sm + 4096;  // [64][65]
  for (int i = t; i < 4096; i += 256) pl[i] = xp[i];
  __syncthreads();
  for (int i = t; i < 4096; i += 256) {
    int h = i >> 6, w = i & 63;
    float a = bias;
#pragma unroll
    for (int kh = 0; kh < 3; kh++) {
      int hh = h + kh - 1;
      if (hh < 0 || hh > 63) continue;
#pragma unroll
      for (int kw = 0; kw < 3; kw++) {
        int ww = w + kw - 1;
        if (ww < 0 || ww > 63) continue;
        a += pl[hh * 64 + ww] * wreg[kh * 3 + kw];
      }
    }
    float r = silu_f(a);
    xp[i] = r;
    po[w * 65 + h] = r;
  }
  __syncthreads();
  for (int i = t; i < 4096; i += 256) xt[i] = po[(i >> 6) * 65 + (i & 63)];
}

// unit: 0..255 (k = unit>>6, l0 = (unit&63)*64). smem: 8448 floats.
__device__ __forceinline__ void ph_xdbl(float* __restrict__ ws, float* sm, int t, int unit) {
  int k = unit >> 6;
  int l0 = (unit & 63) * 64;
  int lane = t & 63;
  int grp = t >> 6;
  float* xtile = sm;  // [64][132]
  const float* pk = ws + ((k & 1) ? OFF_XT0 : OFF_XC0);
  int rev = (k >= 2);
  for (int i = t; i < 8192; i += 256) {
    int d = i >> 6, ll = i & 63;
    int idx = rev ? (4095 - (l0 + ll)) : (l0 + ll);
    xtile[ll * 132 + d] = pk[d * LSEQ + idx];
  }
  __syncthreads();
  const float* __restrict__ xpw = ws + IN_XPW0 + k * 4608;
  float acc[9];
#pragma unroll
  for (int i = 0; i < 9; i++) acc[i] = 0.f;
  for (int q = 0; q < 32; q++) {
    float4 x4 = *(const float4*)&xtile[lane * 132 + 4 * q];
#pragma unroll
    for (int i = 0; i < 9; i++) {
      float4 w4 = *(const float4*)&xpw[(grp * 9 + i) * 128 + 4 * q];  // s_load
      acc[i] += x4.x * w4.x + x4.y * w4.y + x4.z * w4.z + x4.w * w4.w;
    }
  }
  float* xd = ws + OFF_XDBL + k * 36 * LSEQ;
#pragma unroll
  for (int i = 0; i < 9; i++) xd[(grp * 9 + i) * LSEQ + l0 + lane] = acc[i];
}

// gc: 0..1023 global chunk unit; half = t>>7. smem per half: SA_HALF floats.
__device__ __forceinline__ void ph_scanA(float* __restrict__ ws, float* sm, int t, int gc) {
  int half = t >> 7, d = t & 127;
  int s = gc >> 9, r = gc & 511, k = r >> 7, c = r & 127;
  float* base = sm + half * SA_HALF;
  float* us = base;           // [128][33]
  float* dtr = base + 4224;   // [4][16]
  float* Bt = base + 4288;    // 16 rows stride 20
  const float* xd_dt = ws + OFF_XDBL + k * 36 * LSEQ;
  const float* Bb = xd_dt + 4 * LSEQ;
  const float* alog = ws + (s ? IN_AL0 : IN_AL1);
  const float* dtw = ws + (s ? IN_DTW0 : IN_DTW1);
  const float* dtb = ws + (s ? IN_DTB0 : IN_DTB1);
  const float* plane = ws + (s ? OFF_XC1 : OFF_XC0) + ((k & 1) ? 2 * DI * LSEQ : 0);
  int rev = (k >= 2);
  int l0 = c * CLEN;
  int mb = rev ? (4064 - l0) : l0;
  __syncthreads();
  for (int i = d; i < 4096; i += 128) {
    int d2 = i >> 5, c2 = i & 31;
    us[d2 * 33 + c2] = plane[d2 * LSEQ + mb + c2];  // coalesced
  }
  float A[NSTATE];
#pragma unroll
  for (int n = 0; n < NSTATE; n++) A[n] = -__expf(alog[(k * DI + d) * NSTATE + n]);
  bool fastp = true;
#pragma unroll
  for (int n = 1; n < NSTATE; n++)
    fastp = fastp && (fabsf(A[n] - (float)(n + 1) * A[0]) <= 1e-3f * fabsf(A[n]));
  float4 wrv = *(const float4*)&dtw[(k * DI + d) * 4];
  float dbias = dtb[k * DI + d];
  float h[NSTATE];
#pragma unroll
  for (int n = 0; n < NSTATE; n++) h[n] = 0.f;
  float sde = 0.f;
  for (int tile = 0; tile < 2; tile++) {
    int l0t = l0 + tile * 16;
    __syncthreads();
    if (d < 64) dtr[(d >> 4) * 16 + (d & 15)] = xd_dt[(d >> 4) * LSEQ + l0t + (d & 15)];
#pragma unroll
    for (int q = 0; q < 2; q++) {
      int i = d + q * 128;
      int n = i >> 4, j = i & 15;
      Bt[j * 20 + n] = Bb[n * LSEQ + l0t + j];
    }
    __syncthreads();
    float de[16];
#pragma unroll
    for (int j = 0; j < 16; j++) {
      de[j] = softplus_f(dtr[j] * wrv.x + dtr[16 + j] * wrv.y + dtr[32 + j] * wrv.z +
                         dtr[48 + j] * wrv.w + dbias);
      sde += de[j];
    }
#pragma unroll
    for (int j = 0; j < 16; j++) {
      int cc = tile * 16 + j;
      float u = us[d * 33 + (rev ? 31 - cc : cc)];
      float duj = de[j] * u;
      float4 b0 = *(const float4*)&Bt[j * 20 + 0];
      float4 b1 = *(const float4*)&Bt[j * 20 + 4];
      float4 b2 = *(const float4*)&Bt[j * 20 + 8];
      float4 b3 = *(const float4*)&Bt[j * 20 + 12];
      float bv[16] = {b0.x, b0.y, b0.z, b0.w, b1.x, b1.y, b1.z, b1.w,
                      b2.x, b2.y, b2.z, b2.w, b3.x, b3.y, b3.z, b3.w};
      if (fastp) {
        float e1 = __expf(de[j] * A[0]);
        float p = e1;
#pragma unroll
        for (int n = 0; n < NSTATE; n++) {
          h[n] = p * h[n] + duj * bv[n];
          p *= e1;
        }
      } else {
#pragma unroll
        for (int n = 0; n < NSTATE; n++) {
          float da = __expf(de[j] * A[n]);
          h[n] = da * h[n] + duj * bv[n];
        }
      }
    }
  }
  int chainb = ((s * 4 + k) * DI + d) * NSTATE;
  float* Pp = ws + OFF_CHP + c * CHTOT + chainb;
  float* Sp = ws + OFF_CHS + c * CHTOT + chainb;
#pragma unroll
  for (int q = 0; q < 4; q++) {
    ((float4*)Pp)[q] = make_float4(__expf(A[4 * q] * sde), __expf(A[4 * q + 1] * sde),
                                   __expf(A[4 * q + 2] * sde), __expf(A[4 * q + 3] * sde));
    ((float4*)Sp)[q] = make_float4(h[4 * q], h[4 * q + 1], h[4 * q + 2], h[4 * q + 3]);
  }
}

__device__ __forceinline__ void ph_comb(float* __restrict__ ws, int chain) {
  float* P = ws + OFF_CHP + chain;
  float* S = ws + OFF_CHS + chain;
  float h = 0.f;
  for (int g = 0; g < NCHUNK; g += 8) {
    float p[8], sv[8];
#pragma unroll
    for (int i = 0; i < 8; i++) {
      p[i] = P[(g + i) * CHTOT];
      sv[i] = S[(g + i) * CHTOT];
    }
#pragma unroll
    for (int i = 0; i < 8; i++) {
      P[(g + i) * CHTOT] = h;
      h = p[i] * h + sv[i];
    }
  }
}

__device__ __forceinline__ void ph_scanB(float* __restrict__ ws, float* sm, int t, int gc) {
  int half = t >> 7, d = t & 127;
  int s = gc >> 9, r = gc & 511, k = r >> 7, c = r & 127;
  float* base = sm + half * SB_HALF;
  float* us = base;
  float* dtr = base + 4224;
  float* Bt = base + 4288;
  float* Ct = base + 4608;
  const float* xd_dt = ws + OFF_XDBL + k * 36 * LSEQ;
  const float* Bb = xd_dt + 4 * LSEQ;
  const float* Cb = xd_dt + 20 * LSEQ;
  const float* alog = ws + (s ? IN_AL0 : IN_AL1);
  const float* dtw = ws + (s ? IN_DTW0 : IN_DTW1);
  const float* dtb = ws + (s ? IN_DTB0 : IN_DTB1);
  const float* Dvec = ws + (s ? IN_DS0 : IN_DS1);
  const float* plane = ws + (s ? OFF_XC1 : OFF_XC0) + ((k & 1) ? 2 * DI * LSEQ : 0);
  float* oyb = ws + OFF_OY + (s * NK + k) * (LSEQ * DI);
  int rev = (k >= 2);
  int l0 = c * CLEN;
  int mb = rev ? (4064 - l0) : l0;
  __syncthreads();
  for (int i = d; i < 4096; i += 128) {
    int d2 = i >> 5, c2 = i & 31;
    us[d2 * 33 + c2] = plane[d2 * LSEQ + mb + c2];
  }
  float A[NSTATE];
#pragma unroll
  for (int n = 0; n < NSTATE; n++) A[n] = -__expf(alog[(k * DI + d) * NSTATE + n]);
  bool fastp = true;
#pragma unroll
  for (int n = 1; n < NSTATE; n++)
    fastp = fastp && (fabsf(A[n] - (float)(n + 1) * A[0]) <= 1e-3f * fabsf(A[n]));
  float4 wrv = *(const float4*)&dtw[(k * DI + d) * 4];
  float dbias = dtb[k * DI + d];
  float Dv = Dvec[k * DI + d];
  int chainb = ((s * 4 + k) * DI + d) * NSTATE;
  const float* Hp = ws + OFF_CHP + c * CHTOT + chainb;
  float h[NSTATE];
#pragma unroll
  for (int q = 0; q < 4; q++) {
    float4 hv = ((const float4*)Hp)[q];
    h[4 * q] = hv.x; h[4 * q + 1] = hv.y; h[4 * q + 2] = hv.z; h[4 * q + 3] = hv.w;
  }
  for (int tile = 0; tile < 2; tile++) {
    int l0t = l0 + tile * 16;
    __syncthreads();
    if (d < 64) dtr[(d >> 4) * 16 + (d & 15)] = xd_dt[(d >> 4) * LSEQ + l0t + (d & 15)];
#pragma unroll
    for (int q = 0; q < 2; q++) {
      int i = d + q * 128;
      int n = i >> 4, j = i & 15;
      Bt[j * 20 + n] = Bb[n * LSEQ + l0t + j];
      Ct[j * 20 + n] = Cb[n * LSEQ + l0t + j];
    }
    __syncthreads();
    float de[16];
#pragma unroll
    for (int j = 0; j < 16; j++) {
      de[j] = softplus_f(dtr[j] * wrv.x + dtr[16 + j] * wrv.y + dtr[32 + j] * wrv.z +
                         dtr[48 + j] * wrv.w + dbias);
    }
#pragma unroll
    for (int j = 0; j < 16; j++) {
      int cc = tile * 16 + j;
      float u = us[d * 33 + (rev ? 31 - cc : cc)];
      float duj = de[j] * u;
      float4 b0 = *(const float4*)&Bt[j * 20 + 0];
      float4 b1 = *(const float4*)&Bt[j * 20 + 4];
      float4 b2 = *(const float4*)&Bt[j * 20 + 8];
      float4 b3 = *(const float4*)&Bt[j * 20 + 12];
      float bv[16] = {b0.x, b0.y, b0.z, b0.w, b1.x, b1.y, b1.z, b1.w,
                      b2.x, b2.y, b2.z, b2.w, b3.x, b3.y, b3.z, b3.w};
      float4 c0 = *(const float4*)&Ct[j * 20 + 0];
      float4 c1 = *(const float4*)&Ct[j * 20 + 4];
      float4 c2 = *(const float4*)&Ct[j * 20 + 8];
      float4 c3 = *(const float4*)&Ct[j * 20 + 12];
      float cv[16] = {c0.x, c0.y, c0.z, c0.w, c1.x, c1.y, c1.z, c1.w,
                      c2.x, c2.y, c2.z, c2.w, c3.x, c3.y, c3.z, c3.w};
      float y = 0.f;
      if (fastp) {
        float e1 = __expf(de[j] * A[0]);
        float p = e1;
#pragma unroll
        for (int n = 0; n < NSTATE; n++) {
          h[n] = p * h[n] + duj * bv[n];
          y += h[n] * cv[n];
          p *= e1;
        }
      } else {
#pragma unroll
        for (int n = 0; n < NSTATE; n++) {
          float da = __expf(de[j] * A[n]);
          h[n] = da * h[n] + duj * bv[n];
          y += h[n] * cv[n];
        }
      }
      y += u * Dv;
      oyb[(l0t + j) * DI + d] = y;
    }
  }
}

// unit: 0..511 (b = unit>>8, l0 = (unit&255)*16). smem: 10368 floats.
__device__ __forceinline__ void ph_post(const float* __restrict__ ws, float* sm, int t,
                                        int unit, int f32, void* __restrict__ out) {
  int b = unit >> 8;
  int l0 = (unit & 255) * 16;
  const float* oy = ws + OFF_OY + b * (NK * LSEQ * DI);
  const float* sz = ws + (b ? OFF_SZ1 : OFF_SZ0);
  const float* g = ws + (b ? IN_G1 : IN_G0);
  const float* be = ws + (b ? IN_B1 : IN_B0);
  const float* wo = ws + (b ? IN_WO1 : IN_WO0);
  float* yl = sm;         // [16][132]
  float* wl = sm + 2112;  // [64][129]
  for (int i = t; i < 8192; i += 256) wl[(i >> 7) * 129 + (i & 127)] = wo[i];
  int wv = t >> 6, lane = t & 63;
  float g1 = g[lane], g2 = g[lane + 64];
  float be1 = be[lane], be2 = be[lane + 64];
#pragma unroll
  for (int i = 0; i < 4; i++) {
    int r = wv + 4 * i;
    int l = l0 + r;
    int lt = ((l & 63) << 6) | (l >> 6);
    float v1 = oy[(0 * LSEQ + l) * DI + lane] + oy[(1 * LSEQ + lt) * DI + lane] +
               oy[(2 * LSEQ + (4095 - l)) * DI + lane] +
               oy[(3 * LSEQ + (4095 - lt)) * DI + lane];
    float v2 = oy[(0 * LSEQ + l) * DI + lane + 64] + oy[(1 * LSEQ + lt) * DI + lane + 64] +
               oy[(2 * LSEQ + (4095 - l)) * DI + lane + 64] +
               oy[(3 * LSEQ + (4095 - lt)) * DI + lane + 64];
    float s1 = v1 + v2, s2 = v1 * v1 + v2 * v2;
#pragma unroll
    for (int m = 1; m < 64; m <<= 1) {
      s1 += __shfl_xor(s1, m);
      s2 += __shfl_xor(s2, m);
    }
    float mean = s1 * (1.f / 128.f);
    float var = s2 * (1.f / 128.f) - mean * mean;
    float inv = rsqrtf(var + 1e-5f);
    yl[r * 132 + lane] = ((v1 - mean) * inv * g1 + be1) * sz[l * 128 + lane];
    yl[r * 132 + lane + 64] = ((v2 - mean) * inv * g2 + be2) * sz[l * 128 + lane + 64];
  }
  __syncthreads();
  int m = t & 63, rg = t >> 6;
  float acc0 = 0.f, acc1 = 0.f, acc2 = 0.f, acc3 = 0.f;
  for (int q = 0; q < 32; q++) {
    float w0 = wl[m * 129 + 4 * q], w1 = wl[m * 129 + 4 * q + 1];
    float w2 = wl[m * 129 + 4 * q + 2], w3 = wl[m * 129 + 4 * q + 3];
    float4 y0 = *(const float4*)&yl[(rg + 0) * 132 + 4 * q];
    float4 y1 = *(const float4*)&yl[(rg + 4) * 132 + 4 * q];
    float4 y2 = *(const float4*)&yl[(rg + 8) * 132 + 4 * q];
    float4 y3 = *(const float4*)&yl[(rg + 12) * 132 + 4 * q];
    acc0 += y0.x * w0 + y0.y * w1 + y0.z * w2 + y0.w * w3;
    acc1 += y1.x * w0 + y1.y * w1 + y1.z * w2 + y1.w * w3;
    acc2 += y2.x * w0 + y2.y * w1 + y2.z * w2 + y2.w * w3;
    acc3 += y3.x * w0 + y3.y * w1 + y3.z * w2 + y3.w * w3;
  }
  float accs[4] = {acc0, acc1, acc2, acc3};
#pragma unroll
  for (int i = 0; i < 4; i++) {
    int l = l0 + rg + 4 * i;
    int oi = b * (LSEQ * 64) + l * 64 + m;
    if (f32) ((float*)out)[oi] = accs[i];
    else ((bf16*)out)[oi] = __float2bfloat16(accs[i]);
  }
}

// ================= mega kernel (cooperative, 256 blocks) =================
__global__ __launch_bounds__(256, 2) void k_mega(Ptrs pt, const void* probe,
                                                 void* out, float* __restrict__ ws) {
  cg::grid_group grid = cg::this_grid();
  __shared__ __align__(16) float sm[SMEM_FLOATS];
  __shared__ int sf32;
  int t = threadIdx.x;
  int u = blockIdx.x;
  int f32 = probe_f32(probe, t, &sf32);

  ph_convert(pt, f32, ws, u * 256 + t, NBLK * 256);
  grid.sync();
  for (int it = 0; it < 2; it++) {
    if (it) __syncthreads();
    ph_inproj(ws, sm, t, u + 256 * it);
  }
  grid.sync();
  ph_conv(ws, sm, t, u);
  grid.sync();
  ph_xdbl(ws, sm, t, u);
  grid.sync();
  for (int it = 0; it < 2; it++) ph_scanA(ws, sm, t, (u + 256 * it) * 2 + (t >> 7));
  grid.sync();
  if (u < 64) ph_comb(ws, u * 256 + t);
  grid.sync();
  for (int it = 0; it < 2; it++) ph_scanB(ws, sm, t, (u + 256 * it) * 2 + (t >> 7));
  grid.sync();
  for (int it = 0; it < 2; it++) {
    if (it) __syncthreads();
    ph_post(ws, sm, t, u + 256 * it, f32, out);
  }
}

// ================= discrete fallback kernels =================
__global__ __launch_bounds__(256) void k_convert(Ptrs pt, const void* probe,
                                                 float* __restrict__ ws) {
  __shared__ int sf32;
  int t = threadIdx.x;
  int f32 = probe_f32(probe, t, &sf32);
  ph_convert(pt, f32, ws, blockIdx.x * 256 + t, gridDim.x * 256);
}
__global__ __launch_bounds__(256) void k_inproj2(float* __restrict__ ws) {
  __shared__ __align__(16) float sm[2176];
  ph_inproj(ws, sm, threadIdx.x, blockIdx.x);
}
__global__ __launch_bounds__(256) void k_conv2(float* __restrict__ ws) {
  __shared__ __align__(16) float sm[8256];
  ph_conv(ws, sm, threadIdx.x, blockIdx.x);
}
__global__ __launch_bounds__(256) void k_xdbl2(float* __restrict__ ws) {
  __shared__ __align__(16) float sm[8448];
  ph_xdbl(ws, sm, threadIdx.x, blockIdx.x);
}
__global__ __launch_bounds__(256, 2) void k_scanA2(float* __restrict__ ws) {
  __shared__ __align__(16) float sm[2 * SA_HALF];
  ph_scanA(ws, sm, threadIdx.x, blockIdx.x * 2 + (threadIdx.x >> 7));
}
__global__ __launch_bounds__(256) void k_comb2(float* __restrict__ ws) {
  ph_comb(ws, blockIdx.x * 256 + threadIdx.x);
}
__global__ __launch_bounds__(256, 2) void k_scanB2(float* __restrict__ ws) {
  __shared__ __align__(16) float sm[2 * SB_HALF];
  ph_scanB(ws, sm, threadIdx.x, blockIdx.x * 2 + (threadIdx.x >> 7));
}
__global__ __launch_bounds__(256) void k_post2(const float* __restrict__ ws,
                                               const void* probe, void* __restrict__ out) {
  __shared__ __align__(16) float sm[SMEM_FLOATS];
  __shared__ int sf32;
  int t = threadIdx.x;
  int f32 = probe_f32(probe, t, &sf32);
  ph_post(ws, sm, t, blockIdx.x, f32, out);
}

extern "C" void kernel_launch(void* const* d_in, const int* in_sizes, int n_in,
                              void* d_out, int out_size, void* d_ws, size_t ws_size,
                              hipStream_t stream) {
  float* ws = (float*)d_ws;

  Ptrs pt;
  const int map[23] = {0, 1, 2, 3, 4, 5, 6, 7, 8, 10, 11, 12, 13, 14, 15, 16, 17,
                       18, 19, 20, 21, 22, 23};
  for (int j = 0; j < 23; j++) pt.p[j] = d_in[map[j]];
  const void* probe = d_in[2];
  void* outp = d_out;

  void* args[] = {&pt, &probe, &outp, &ws};
  hipError_t err = hipLaunchCooperativeKernel((void*)k_mega, dim3(NBLK), dim3(256),
                                              args, 0, stream);
  if (err != hipSuccess) {
    (void)hipGetLastError();  // clear sticky error, fall back to discrete chain
    k_convert<<<dim3(512), 256, 0, stream>>>(pt, probe, ws);
    k_inproj2<<<dim3(512), 256, 0, stream>>>(ws);
    k_conv2<<<dim3(256), 256, 0, stream>>>(ws);
    k_xdbl2<<<dim3(256), 256, 0, stream>>>(ws);
    k_scanA2<<<dim3(512), 256, 0, stream>>>(ws);
    k_comb2<<<dim3(64), 256, 0, stream>>>(ws);
    k_scanB2<<<dim3(512), 256, 0, stream>>>(ws);
    k_post2<<<dim3(512), 256, 0, stream>>>(ws, probe, d_out);
  }
}

// Round 11
// 389.043 us; speedup vs baseline: 1.4698x; 1.4698x over previous
//
#include <hip/hip_runtime.h>
#include <hip/hip_bf16.h>
#include <math.h>

typedef __hip_bfloat16 bf16;

// ---------------- problem constants ----------------
#define LSEQ 4096
#define DI 128
#define NSTATE 16
#define NK 4
#define NCHUNK 256
#define CLEN 16
#define CHTOT 16384   // 2 scans * 4 k * 128 d * 16 n

// ---------------- workspace layout (no input staging; raw reads) ----------------
#define OFF_XC0  0
#define OFF_XC1  (OFF_XC0 + DI*LSEQ)
#define OFF_XT0  (OFF_XC1 + DI*LSEQ)
#define OFF_XT1  (OFF_XT0 + DI*LSEQ)
#define OFF_SZ0  (OFF_XT1 + DI*LSEQ)
#define OFF_SZ1  (OFF_SZ0 + LSEQ*DI)
#define OFF_XDBL (OFF_SZ1 + LSEQ*DI)        // [k][36][l]
#define OFF_CHP  (OFF_XDBL + NK*36*LSEQ)    // [chunk][chain]; after comb = h-init
#define OFF_CHS  (OFF_CHP + NCHUNK*CHTOT)
#define OFF_OY   (OFF_CHS + NCHUNK*CHTOT)   // [s][k][l][d]
#define WS_FLOATS (OFF_OY + 2*NK*LSEQ*DI)   // ~16.3M floats = 65 MB

#define SA_HALF 2560   // us 2176 + dtr 64 + Bt 320
#define SB_HALF 2880   // + Ct 320

__device__ __forceinline__ float softplus_f(float x) {
  return x > 20.f ? x : __logf(1.f + __expf(x));
}
__device__ __forceinline__ float silu_f(float x) {
  return x / (1.f + __expf(-x));
}
// raw input read with runtime dtype (branch is wave-uniform)
__device__ __forceinline__ float ldraw(const void* p, int i, int f32) {
  return f32 ? ((const float*)p)[i] : __bfloat162float(((const bf16*)p)[i]);
}
// dtype probe: even bf16 halves of an fp32 buffer have random exponents
__device__ __forceinline__ int probe_f32(const void* probe, int t, int* sh) {
  if (t < 64) {
    int idx = 2 * ((t * 127) & 4095);
    float v = __bfloat162float(((const bf16*)probe)[idx]);
    int weird = (!(v == v)) || (fabsf(v) > 4.0f);
    unsigned long long m = __ballot(weird);
    if (t == 0) *sh = (__popcll(m) >= 8) ? 1 : 0;
  }
  __syncthreads();
  return *sh;
}

// ---------------- K1: in_proj (raw x, raw w) ----------------
__global__ __launch_bounds__(256) void k_inproj(const void* x0, const void* x1,
                                                const void* w0, const void* w1,
                                                const void* probe, float* __restrict__ ws) {
  __shared__ __align__(16) float sm[2176];
  __shared__ int sf32;
  int t = threadIdx.x;
  int f32 = probe_f32(probe, t, &sf32);
  int unit = blockIdx.x;
  int b = unit >> 8;
  int l0 = (unit & 255) * 16;
  const void* x = b ? x1 : x0;
  const void* w = b ? w1 : w0;
  float* xi = ws + (b ? OFF_XC1 : OFF_XC0);
  float* sz = ws + (b ? OFF_SZ1 : OFF_SZ0);
  int j = t;  // output channel 0..255
  float wr[64];
#pragma unroll
  for (int c = 0; c < 64; c++) wr[c] = ldraw(w, j * 64 + c, f32);
  float acc[16];
#pragma unroll
  for (int p = 0; p < 16; p++) acc[p] = 0.f;
#pragma unroll 4
  for (int p = 0; p < 16; p++) {
    int base = (l0 + p) * 64;  // block-uniform -> scalar loads
#pragma unroll
    for (int c = 0; c < 64; c++) acc[p] += ldraw(x, base + c, f32) * wr[c];
  }
  if (j < 128) {
#pragma unroll
    for (int p = 0; p < 16; p++) sm[j * 17 + p] = acc[p];
  } else {
    int d = j - 128;
#pragma unroll
    for (int p = 0; p < 16; p++) sz[(l0 + p) * 128 + d] = silu_f(acc[p]);
  }
  __syncthreads();
#pragma unroll
  for (int r8 = 0; r8 < 8; r8++) {
    int row = (t >> 4) + 16 * r8, col = t & 15;
    xi[row * LSEQ + l0 + col] = sm[row * 17 + col];  // 16-consecutive stores
  }
}

// ---------------- K2: depthwise conv + SiLU; emit xc + xcT (raw weights) ----------------
__global__ __launch_bounds__(256) void k_conv(const void* cw0, const void* cb0,
                                              const void* cw1, const void* cb1,
                                              const void* probe, float* __restrict__ ws) {
  __shared__ __align__(16) float sm[8256];
  __shared__ int sf32;
  int t = threadIdx.x;
  int f32 = probe_f32(probe, t, &sf32);
  int b = blockIdx.x >> 7, d = blockIdx.x & 127;
  const void* cw = b ? cw1 : cw0;
  float bias = ldraw(b ? cb1 : cb0, d, f32);
  float* xp = ws + (b ? OFF_XC1 : OFF_XC0) + d * LSEQ;
  float* xt = ws + (b ? OFF_XT1 : OFF_XT0) + d * LSEQ;
  float wreg[9];
#pragma unroll
  for (int i = 0; i < 9; i++) wreg[i] = ldraw(cw, d * 9 + i, f32);
  float* pl = sm;         // [64][64]
  float* po = sm + 4096;  // [64][65]
  for (int i = t; i < 4096; i += 256) pl[i] = xp[i];
  __syncthreads();
  for (int i = t; i < 4096; i += 256) {
    int h = i >> 6, w = i & 63;
    float a = bias;
#pragma unroll
    for (int kh = 0; kh < 3; kh++) {
      int hh = h + kh - 1;
      if (hh < 0 || hh > 63) continue;
#pragma unroll
      for (int kw = 0; kw < 3; kw++) {
        int ww = w + kw - 1;
        if (ww < 0 || ww > 63) continue;
        a += pl[hh * 64 + ww] * wreg[kh * 3 + kw];
      }
    }
    float r = silu_f(a);
    xp[i] = r;
    po[w * 65 + h] = r;
  }
  __syncthreads();
  for (int i = t; i < 4096; i += 256) xt[i] = po[(i >> 6) * 65 + (i & 63)];
}

// ---------------- K3: x_dbl (raw x_proj_w0, staged in LDS) ----------------
__global__ __launch_bounds__(256) void k_xdbl(const void* xpw0, const void* probe,
                                              float* __restrict__ ws) {
  __shared__ __align__(16) float sm[8448 + 4608];
  __shared__ int sf32;
  int t = threadIdx.x;
  int f32 = probe_f32(probe, t, &sf32);
  int k = blockIdx.x >> 6;
  int l0 = (blockIdx.x & 63) * 64;
  int lane = t & 63;
  int grp = t >> 6;
  float* xtile = sm;        // [64][132]
  float* wl = sm + 8448;    // [36][128]
  const float* pk = ws + ((k & 1) ? OFF_XT0 : OFF_XC0);
  int rev = (k >= 2);
  for (int i = t; i < 8192; i += 256) {
    int d = i >> 6, ll = i & 63;
    int idx = rev ? (4095 - (l0 + ll)) : (l0 + ll);
    xtile[ll * 132 + d] = pk[d * LSEQ + idx];
  }
  for (int i = t; i < 4608; i += 256) wl[i] = ldraw(xpw0, k * 4608 + i, f32);
  __syncthreads();
  float acc[9];
#pragma unroll
  for (int i = 0; i < 9; i++) acc[i] = 0.f;
  for (int q = 0; q < 32; q++) {
    float4 x4 = *(const float4*)&xtile[lane * 132 + 4 * q];
#pragma unroll
    for (int i = 0; i < 9; i++) {
      float4 w4 = *(const float4*)&wl[(grp * 9 + i) * 128 + 4 * q];  // broadcast
      acc[i] += x4.x * w4.x + x4.y * w4.y + x4.z * w4.z + x4.w * w4.w;
    }
  }
  float* xd = ws + OFF_XDBL + k * 36 * LSEQ;
#pragma unroll
  for (int i = 0; i < 9; i++) xd[(grp * 9 + i) * LSEQ + l0 + lane] = acc[i];
}

// ---------------- K4: scan pass 1 — per-chunk (P, S). 2 chunk-units/block ----------------
// cross-wiring: s=0 uses dt1/A1; s=1 uses dt0/A0. Fast path: A[n]=(n+1)A[0].
__global__ __launch_bounds__(256, 2) void k_scanA(const void* al0, const void* al1,
                                                  const void* dtw0, const void* dtw1,
                                                  const void* dtb0, const void* dtb1,
                                                  const void* probe, float* __restrict__ ws) {
  __shared__ __align__(16) float sm[2 * SA_HALF];
  __shared__ int sf32;
  int t = threadIdx.x;
  int f32 = probe_f32(probe, t, &sf32);
  int half = t >> 7, d = t & 127;
  int gc = blockIdx.x * 2 + half;            // 0..2047
  int s = gc >> 10, k = (gc >> 8) & 3, c = gc & 255;
  float* base = sm + half * SA_HALF;
  float* us = base;          // [128][17]
  float* dtr = base + 2176;  // [4][16]
  float* Bt = base + 2240;   // 16 rows stride 20
  const float* xd_dt = ws + OFF_XDBL + k * 36 * LSEQ;
  const float* Bb = xd_dt + 4 * LSEQ;
  const void* alog = s ? al0 : al1;
  const void* dtw = s ? dtw0 : dtw1;
  const void* dtb = s ? dtb0 : dtb1;
  const float* plane = ws + (s ? OFF_XC1 : OFF_XC0) + ((k & 1) ? 2 * DI * LSEQ : 0);
  int rev = (k >= 2);
  int l0 = c * CLEN;
  int mb = rev ? (4080 - l0) : l0;
  for (int i = d; i < 2048; i += 128) {
    int d2 = i >> 4, c2 = i & 15;
    us[d2 * 17 + c2] = plane[d2 * LSEQ + mb + c2];  // coalesced
  }
  if (d < 64) dtr[(d >> 4) * 16 + (d & 15)] = xd_dt[(d >> 4) * LSEQ + l0 + (d & 15)];
#pragma unroll
  for (int q = 0; q < 2; q++) {
    int i = d + q * 128;
    int n = i >> 4, j = i & 15;
    Bt[j * 20 + n] = Bb[n * LSEQ + l0 + j];
  }
  float A[NSTATE];
#pragma unroll
  for (int n = 0; n < NSTATE; n++) A[n] = -__expf(ldraw(alog, (k * DI + d) * NSTATE + n, f32));
  bool fastp = true;
#pragma unroll
  for (int n = 1; n < NSTATE; n++)
    fastp = fastp && (fabsf(A[n] - (float)(n + 1) * A[0]) <= 1e-3f * fabsf(A[n]));
  float w0 = ldraw(dtw, (k * DI + d) * 4 + 0, f32), w1 = ldraw(dtw, (k * DI + d) * 4 + 1, f32);
  float w2 = ldraw(dtw, (k * DI + d) * 4 + 2, f32), w3 = ldraw(dtw, (k * DI + d) * 4 + 3, f32);
  float dbias = ldraw(dtb, k * DI + d, f32);
  float h[NSTATE];
#pragma unroll
  for (int n = 0; n < NSTATE; n++) h[n] = 0.f;
  float sde = 0.f;
  __syncthreads();
  float de[16];
#pragma unroll
  for (int j = 0; j < 16; j++) {
    de[j] = softplus_f(dtr[j] * w0 + dtr[16 + j] * w1 + dtr[32 + j] * w2 + dtr[48 + j] * w3 +
                       dbias);
    sde += de[j];
  }
#pragma unroll
  for (int j = 0; j < 16; j++) {
    float u = us[d * 17 + (rev ? 15 - j : j)];
    float duj = de[j] * u;
    float4 b0 = *(const float4*)&Bt[j * 20 + 0];
    float4 b1 = *(const float4*)&Bt[j * 20 + 4];
    float4 b2 = *(const float4*)&Bt[j * 20 + 8];
    float4 b3 = *(const float4*)&Bt[j * 20 + 12];
    float bv[16] = {b0.x, b0.y, b0.z, b0.w, b1.x, b1.y, b1.z, b1.w,
                    b2.x, b2.y, b2.z, b2.w, b3.x, b3.y, b3.z, b3.w};
    if (fastp) {
      float e1 = __expf(de[j] * A[0]);
      float p = e1;
#pragma unroll
      for (int n = 0; n < NSTATE; n++) {
        h[n] = p * h[n] + duj * bv[n];
        p *= e1;
      }
    } else {
#pragma unroll
      for (int n = 0; n < NSTATE; n++) {
        float da = __expf(de[j] * A[n]);
        h[n] = da * h[n] + duj * bv[n];
      }
    }
  }
  int chainb = ((s * 4 + k) * DI + d) * NSTATE;
  float* Pp = ws + OFF_CHP + c * CHTOT + chainb;
  float* Sp = ws + OFF_CHS + c * CHTOT + chainb;
#pragma unroll
  for (int q = 0; q < 4; q++) {
    ((float4*)Pp)[q] = make_float4(__expf(A[4 * q] * sde), __expf(A[4 * q + 1] * sde),
                                   __expf(A[4 * q + 2] * sde), __expf(A[4 * q + 3] * sde));
    ((float4*)Sp)[q] = make_float4(h[4 * q], h[4 * q + 1], h[4 * q + 2], h[4 * q + 3]);
  }
}

// ---------------- K5: combine 256 chunk summaries; CHP -> h-init in place ----------------
__global__ __launch_bounds__(256) void k_comb(float* __restrict__ ws) {
  int chain = blockIdx.x * 256 + threadIdx.x;
  float* P = ws + OFF_CHP + chain;
  float* S = ws + OFF_CHS + chain;
  float h = 0.f;
  for (int g = 0; g < NCHUNK; g += 8) {
    float p[8], sv[8];
#pragma unroll
    for (int i = 0; i < 8; i++) {
      p[i] = P[(g + i) * CHTOT];
      sv[i] = S[(g + i) * CHTOT];
    }
#pragma unroll
    for (int i = 0; i < 8; i++) {
      P[(g + i) * CHTOT] = h;
      h = p[i] * h + sv[i];
    }
  }
}

// ---------------- K6: scan pass 2 — recompute with h-init, store y+u*D ----------------
__global__ __launch_bounds__(256, 2) void k_scanB(const void* al0, const void* al1,
                                                  const void* dtw0, const void* dtw1,
                                                  const void* dtb0, const void* dtb1,
                                                  const void* ds0, const void* ds1,
                                                  const void* probe, float* __restrict__ ws) {
  __shared__ __align__(16) float sm[2 * SB_HALF];
  __shared__ int sf32;
  int t = threadIdx.x;
  int f32 = probe_f32(probe, t, &sf32);
  int half = t >> 7, d = t & 127;
  int gc = blockIdx.x * 2 + half;
  int s = gc >> 10, k = (gc >> 8) & 3, c = gc & 255;
  float* base = sm + half * SB_HALF;
  float* us = base;
  float* dtr = base + 2176;
  float* Bt = base + 2240;
  float* Ct = base + 2560;
  const float* xd_dt = ws + OFF_XDBL + k * 36 * LSEQ;
  const float* Bb = xd_dt + 4 * LSEQ;
  const float* Cb = xd_dt + 20 * LSEQ;
  const void* alog = s ? al0 : al1;
  const void* dtw = s ? dtw0 : dtw1;
  const void* dtb = s ? dtb0 : dtb1;
  const void* Dvec = s ? ds0 : ds1;
  const float* plane = ws + (s ? OFF_XC1 : OFF_XC0) + ((k & 1) ? 2 * DI * LSEQ : 0);
  float* oyb = ws + OFF_OY + (s * NK + k) * (LSEQ * DI);
  int rev = (k >= 2);
  int l0 = c * CLEN;
  int mb = rev ? (4080 - l0) : l0;
  for (int i = d; i < 2048; i += 128) {
    int d2 = i >> 4, c2 = i & 15;
    us[d2 * 17 + c2] = plane[d2 * LSEQ + mb + c2];
  }
  if (d < 64) dtr[(d >> 4) * 16 + (d & 15)] = xd_dt[(d >> 4) * LSEQ + l0 + (d & 15)];
#pragma unroll
  for (int q = 0; q < 2; q++) {
    int i = d + q * 128;
    int n = i >> 4, j = i & 15;
    Bt[j * 20 + n] = Bb[n * LSEQ + l0 + j];
    Ct[j * 20 + n] = Cb[n * LSEQ + l0 + j];
  }
  float A[NSTATE];
#pragma unroll
  for (int n = 0; n < NSTATE; n++) A[n] = -__expf(ldraw(alog, (k * DI + d) * NSTATE + n, f32));
  bool fastp = true;
#pragma unroll
  for (int n = 1; n < NSTATE; n++)
    fastp = fastp && (fabsf(A[n] - (float)(n + 1) * A[0]) <= 1e-3f * fabsf(A[n]));
  float w0 = ldraw(dtw, (k * DI + d) * 4 + 0, f32), w1 = ldraw(dtw, (k * DI + d) * 4 + 1, f32);
  float w2 = ldraw(dtw, (k * DI + d) * 4 + 2, f32), w3 = ldraw(dtw, (k * DI + d) * 4 + 3, f32);
  float dbias = ldraw(dtb, k * DI + d, f32);
  float Dv = ldraw(Dvec, k * DI + d, f32);
  int chainb = ((s * 4 + k) * DI + d) * NSTATE;
  const float* Hp = ws + OFF_CHP + c * CHTOT + chainb;
  float h[NSTATE];
#pragma unroll
  for (int q = 0; q < 4; q++) {
    float4 hv = ((const float4*)Hp)[q];
    h[4 * q] = hv.x; h[4 * q + 1] = hv.y; h[4 * q + 2] = hv.z; h[4 * q + 3] = hv.w;
  }
  __syncthreads();
  float de[16];
#pragma unroll
  for (int j = 0; j < 16; j++) {
    de[j] = softplus_f(dtr[j] * w0 + dtr[16 + j] * w1 + dtr[32 + j] * w2 + dtr[48 + j] * w3 +
                       dbias);
  }
#pragma unroll
  for (int j = 0; j < 16; j++) {
    float u = us[d * 17 + (rev ? 15 - j : j)];
    float duj = de[j] * u;
    float4 b0 = *(const float4*)&Bt[j * 20 + 0];
    float4 b1 = *(const float4*)&Bt[j * 20 + 4];
    float4 b2 = *(const float4*)&Bt[j * 20 + 8];
    float4 b3 = *(const float4*)&Bt[j * 20 + 12];
    float bv[16] = {b0.x, b0.y, b0.z, b0.w, b1.x, b1.y, b1.z, b1.w,
                    b2.x, b2.y, b2.z, b2.w, b3.x, b3.y, b3.z, b3.w};
    float4 c0 = *(const float4*)&Ct[j * 20 + 0];
    float4 c1 = *(const float4*)&Ct[j * 20 + 4];
    float4 c2 = *(const float4*)&Ct[j * 20 + 8];
    float4 c3 = *(const float4*)&Ct[j * 20 + 12];
    float cv[16] = {c0.x, c0.y, c0.z, c0.w, c1.x, c1.y, c1.z, c1.w,
                    c2.x, c2.y, c2.z, c2.w, c3.x, c3.y, c3.z, c3.w};
    float y = 0.f;
    if (fastp) {
      float e1 = __expf(de[j] * A[0]);
      float p = e1;
#pragma unroll
      for (int n = 0; n < NSTATE; n++) {
        h[n] = p * h[n] + duj * bv[n];
        y += h[n] * cv[n];
        p *= e1;
      }
    } else {
#pragma unroll
      for (int n = 0; n < NSTATE; n++) {
        float da = __expf(de[j] * A[n]);
        h[n] = da * h[n] + duj * bv[n];
        y += h[n] * cv[n];
      }
    }
    y += u * Dv;
    oyb[(l0 + j) * DI + d] = y;
  }
}

// ---------------- K7: 4-dir gather + LN + gate + out_proj (raw g/be/wo) ----------------
__global__ __launch_bounds__(256) void k_post(const void* g0_, const void* be0_,
                                              const void* g1_, const void* be1_,
                                              const void* wo0, const void* wo1,
                                              const void* probe,
                                              const float* __restrict__ ws,
                                              void* __restrict__ out) {
  __shared__ __align__(16) float sm[10368];
  __shared__ int sf32;
  int t = threadIdx.x;
  int f32 = probe_f32(probe, t, &sf32);
  int b = blockIdx.x >> 8;
  int l0 = (blockIdx.x & 255) * 16;
  const float* oy = ws + OFF_OY + b * (NK * LSEQ * DI);
  const float* sz = ws + (b ? OFF_SZ1 : OFF_SZ0);
  const void* g = b ? g1_ : g0_;
  const void* be = b ? be1_ : be0_;
  const void* wo = b ? wo1 : wo0;
  float* yl = sm;         // [16][132]
  float* wl = sm + 2112;  // [64][129]
  for (int i = t; i < 8192; i += 256) wl[(i >> 7) * 129 + (i & 127)] = ldraw(wo, i, f32);
  int wv = t >> 6, lane = t & 63;
  float g1 = ldraw(g, lane, f32), g2 = ldraw(g, lane + 64, f32);
  float be1 = ldraw(be, lane, f32), be2 = ldraw(be, lane + 64, f32);
#pragma unroll
  for (int i = 0; i < 4; i++) {
    int r = wv + 4 * i;
    int l = l0 + r;
    int lt = ((l & 63) << 6) | (l >> 6);
    float v1 = oy[(0 * LSEQ + l) * DI + lane] + oy[(1 * LSEQ + lt) * DI + lane] +
               oy[(2 * LSEQ + (4095 - l)) * DI + lane] +
               oy[(3 * LSEQ + (4095 - lt)) * DI + lane];
    float v2 = oy[(0 * LSEQ + l) * DI + lane + 64] + oy[(1 * LSEQ + lt) * DI + lane + 64] +
               oy[(2 * LSEQ + (4095 - l)) * DI + lane + 64] +
               oy[(3 * LSEQ + (4095 - lt)) * DI + lane + 64];
    float s1 = v1 + v2, s2 = v1 * v1 + v2 * v2;
#pragma unroll
    for (int m = 1; m < 64; m <<= 1) {
      s1 += __shfl_xor(s1, m);
      s2 += __shfl_xor(s2, m);
    }
    float mean = s1 * (1.f / 128.f);
    float var = s2 * (1.f / 128.f) - mean * mean;
    float inv = rsqrtf(var + 1e-5f);
    yl[r * 132 + lane] = ((v1 - mean) * inv * g1 + be1) * sz[l * 128 + lane];
    yl[r * 132 + lane + 64] = ((v2 - mean) * inv * g2 + be2) * sz[l * 128 + lane + 64];
  }
  __syncthreads();
  int m = t & 63, rg = t >> 6;
  float acc0 = 0.f, acc1 = 0.f, acc2 = 0.f, acc3 = 0.f;
  for (int q = 0; q < 32; q++) {
    float w0 = wl[m * 129 + 4 * q], w1 = wl[m * 129 + 4 * q + 1];
    float w2 = wl[m * 129 + 4 * q + 2], w3 = wl[m * 129 + 4 * q + 3];
    float4 y0 = *(const float4*)&yl[(rg + 0) * 132 + 4 * q];
    float4 y1 = *(const float4*)&yl[(rg + 4) * 132 + 4 * q];
    float4 y2 = *(const float4*)&yl[(rg + 8) * 132 + 4 * q];
    float4 y3 = *(const float4*)&yl[(rg + 12) * 132 + 4 * q];
    acc0 += y0.x * w0 + y0.y * w1 + y0.z * w2 + y0.w * w3;
    acc1 += y1.x * w0 + y1.y * w1 + y1.z * w2 + y1.w * w3;
    acc2 += y2.x * w0 + y2.y * w1 + y2.z * w2 + y2.w * w3;
    acc3 += y3.x * w0 + y3.y * w1 + y3.z * w2 + y3.w * w3;
  }
  float accs[4] = {acc0, acc1, acc2, acc3};
#pragma unroll
  for (int i = 0; i < 4; i++) {
    int l = l0 + rg + 4 * i;
    int oi = b * (LSEQ * 64) + l * 64 + m;
    if (f32) ((float*)out)[oi] = accs[i];
    else ((bf16*)out)[oi] = __float2bfloat16(accs[i]);
  }
}

extern "C" void kernel_launch(void* const* d_in, const int* in_sizes, int n_in,
                              void* d_out, int out_size, void* d_ws, size_t ws_size,
                              hipStream_t stream) {
  float* ws = (float*)d_ws;
  const void* probe = d_in[2];  // in_proj0_w

  k_inproj<<<dim3(512), 256, 0, stream>>>(d_in[0], d_in[1], d_in[2], d_in[3], probe, ws);
  k_conv<<<dim3(256), 256, 0, stream>>>(d_in[4], d_in[5], d_in[6], d_in[7], probe, ws);
  k_xdbl<<<dim3(256), 256, 0, stream>>>(d_in[8], probe, ws);
  k_scanA<<<dim3(1024), 256, 0, stream>>>(d_in[14], d_in[15], d_in[10], d_in[11],
                                          d_in[12], d_in[13], probe, ws);
  k_comb<<<dim3(64), 256, 0, stream>>>(ws);
  k_scanB<<<dim3(1024), 256, 0, stream>>>(d_in[14], d_in[15], d_in[10], d_in[11],
                                          d_in[12], d_in[13], d_in[16], d_in[17],
                                          probe, ws);
  k_post<<<dim3(512), 256, 0, stream>>>(d_in[18], d_in[19], d_in[20], d_in[21],
                                        d_in[22], d_in[23], probe, ws, d_out);
}

// Round 12
// 230.346 us; speedup vs baseline: 2.4824x; 1.6890x over previous
//
#include <hip/hip_runtime.h>
#include <hip/hip_bf16.h>
#include <math.h>

typedef __hip_bfloat16 bf16;

// ---------------- problem constants ----------------
#define LSEQ 4096
#define DI 128
#define NSTATE 16
#define NK 4
#define NCHUNK 256
#define CLEN 16
#define CHTOT 16384   // 2 scans * 4 k * 128 d * 16 n

// ---------------- workspace layout ----------------
#define OFF_XC0  0
#define OFF_XC1  (OFF_XC0 + DI*LSEQ)
#define OFF_XT0  (OFF_XC1 + DI*LSEQ)
#define OFF_XT1  (OFF_XT0 + DI*LSEQ)
#define OFF_SZ0  (OFF_XT1 + DI*LSEQ)
#define OFF_SZ1  (OFF_SZ0 + LSEQ*DI)
#define OFF_XDBL (OFF_SZ1 + LSEQ*DI)        // [k][36][l]
#define OFF_CHP  (OFF_XDBL + NK*36*LSEQ)    // [chunk][chain]; after comb = h-init
#define OFF_CHS  (OFF_CHP + NCHUNK*CHTOT)
#define OFF_OY   (OFF_CHS + NCHUNK*CHTOT)   // [s][k][l][d]
#define WS_FLOATS (OFF_OY + 2*NK*LSEQ*DI)

#define SA_HALF 2560   // us 2176 + dtr 64 + Bt 320
#define SB_HALF 2880   // + Ct 320

__device__ __forceinline__ float softplus_f(float x) {
  return x > 20.f ? x : __logf(1.f + __expf(x));
}
__device__ __forceinline__ float silu_f(float x) {
  return x / (1.f + __expf(-x));
}
__device__ __forceinline__ float cvt(float v) { return v; }
__device__ __forceinline__ float cvt(bf16 v) { return __bfloat162float(v); }

// dtype probe: even bf16 halves of an fp32 buffer have random exponents
__device__ __forceinline__ int probe_f32(const void* probe, int t, int* sh) {
  if (t < 64) {
    int idx = 2 * ((t * 127) & 4095);
    float v = __bfloat162float(((const bf16*)probe)[idx]);
    int weird = (!(v == v)) || (fabsf(v) > 4.0f);
    unsigned long long m = __ballot(weird);
    if (t == 0) *sh = (__popcll(m) >= 8) ? 1 : 0;
  }
  __syncthreads();
  return *sh;
}

// ================= phase bodies (compile-time dtype T) =================

template <typename T>
__device__ __forceinline__ void ph_inproj(const void* x0, const void* x1, const void* w0,
                                          const void* w1, float* __restrict__ ws,
                                          float* sm, int t, int unit) {
  int b = unit >> 8;
  int l0 = (unit & 255) * 16;
  const T* __restrict__ x = (const T*)(b ? x1 : x0);
  const T* __restrict__ w = (const T*)(b ? w1 : w0);
  float* xi = ws + (b ? OFF_XC1 : OFF_XC0);
  float* sz = ws + (b ? OFF_SZ1 : OFF_SZ0);
  int j = t;  // output channel 0..255
  float wr[64];
#pragma unroll
  for (int c = 0; c < 64; c++) wr[c] = cvt(w[j * 64 + c]);
  float acc[16];
#pragma unroll
  for (int p = 0; p < 16; p++) acc[p] = 0.f;
#pragma unroll 4
  for (int p = 0; p < 16; p++) {
    const T* xr = x + (l0 + p) * 64;  // block-uniform -> s_load (T=float)
#pragma unroll
    for (int c = 0; c < 64; c++) acc[p] += cvt(xr[c]) * wr[c];
  }
  if (j < 128) {
#pragma unroll
    for (int p = 0; p < 16; p++) sm[j * 17 + p] = acc[p];
  } else {
    int d = j - 128;
#pragma unroll
    for (int p = 0; p < 16; p++) sz[(l0 + p) * 128 + d] = silu_f(acc[p]);
  }
  __syncthreads();
#pragma unroll
  for (int r8 = 0; r8 < 8; r8++) {
    int row = (t >> 4) + 16 * r8, col = t & 15;
    xi[row * LSEQ + l0 + col] = sm[row * 17 + col];  // 16-consecutive stores
  }
}

template <typename T>
__device__ __forceinline__ void ph_conv(const void* cw0, const void* cb0, const void* cw1,
                                        const void* cb1, float* __restrict__ ws,
                                        float* sm, int t, int unit) {
  int b = unit >> 7, d = unit & 127;
  const T* cw = (const T*)(b ? cw1 : cw0);
  float bias = cvt(((const T*)(b ? cb1 : cb0))[d]);
  float* xp = ws + (b ? OFF_XC1 : OFF_XC0) + d * LSEQ;
  float* xt = ws + (b ? OFF_XT1 : OFF_XT0) + d * LSEQ;
  float wreg[9];
#pragma unroll
  for (int i = 0; i < 9; i++) wreg[i] = cvt(cw[d * 9 + i]);
  float* pl = sm;         // [64][64]
  float* po = sm + 4096;  // [64][65]
  for (int i = t; i < 4096; i += 256) pl[i] = xp[i];
  __syncthreads();
  for (int i = t; i < 4096; i += 256) {
    int h = i >> 6, w = i & 63;
    float a = bias;
#pragma unroll
    for (int kh = 0; kh < 3; kh++) {
      int hh = h + kh - 1;
      if (hh < 0 || hh > 63) continue;
#pragma unroll
      for (int kw = 0; kw < 3; kw++) {
        int ww = w + kw - 1;
        if (ww < 0 || ww > 63) continue;
        a += pl[hh * 64 + ww] * wreg[kh * 3 + kw];
      }
    }
    float r = silu_f(a);
    xp[i] = r;
    po[w * 65 + h] = r;
  }
  __syncthreads();
  for (int i = t; i < 4096; i += 256) xt[i] = po[(i >> 6) * 65 + (i & 63)];
}

template <typename T>
__device__ __forceinline__ void ph_xdbl(const void* xpw0, float* __restrict__ ws,
                                        float* sm, int t, int unit) {
  int k = unit >> 6;
  int l0 = (unit & 63) * 64;
  int lane = t & 63;
  int grp = t >> 6;
  float* xtile = sm;      // [64][132]
  float* wl = sm + 8448;  // [36][128]
  const float* pk = ws + ((k & 1) ? OFF_XT0 : OFF_XC0);
  const T* xpw = (const T*)xpw0;
  int rev = (k >= 2);
  for (int i = t; i < 8192; i += 256) {
    int d = i >> 6, ll = i & 63;
    int idx = rev ? (4095 - (l0 + ll)) : (l0 + ll);
    xtile[ll * 132 + d] = pk[d * LSEQ + idx];
  }
  for (int i = t; i < 4608; i += 256) wl[i] = cvt(xpw[k * 4608 + i]);
  __syncthreads();
  float acc[9];
#pragma unroll
  for (int i = 0; i < 9; i++) acc[i] = 0.f;
  for (int q = 0; q < 32; q++) {
    float4 x4 = *(const float4*)&xtile[lane * 132 + 4 * q];
#pragma unroll
    for (int i = 0; i < 9; i++) {
      float4 w4 = *(const float4*)&wl[(grp * 9 + i) * 128 + 4 * q];  // broadcast
      acc[i] += x4.x * w4.x + x4.y * w4.y + x4.z * w4.z + x4.w * w4.w;
    }
  }
  float* xd = ws + OFF_XDBL + k * 36 * LSEQ;
#pragma unroll
  for (int i = 0; i < 9; i++) xd[(grp * 9 + i) * LSEQ + l0 + lane] = acc[i];
}

// cross-wiring: s=0 uses dt1/A1; s=1 uses dt0/A0. Fast path: A[n]=(n+1)A[0].
template <typename T>
__device__ __forceinline__ void ph_scanA(const void* al0, const void* al1, const void* dtw0,
                                         const void* dtw1, const void* dtb0, const void* dtb1,
                                         float* __restrict__ ws, float* sm, int t, int gc) {
  int half = t >> 7, d = t & 127;
  int s = gc >> 10, k = (gc >> 8) & 3, c = gc & 255;
  float* base = sm + half * SA_HALF;
  float* us = base;          // [128][17]
  float* dtr = base + 2176;  // [4][16]
  float* Bt = base + 2240;   // 16 rows stride 20
  const float* xd_dt = ws + OFF_XDBL + k * 36 * LSEQ;
  const float* Bb = xd_dt + 4 * LSEQ;
  const T* alog = (const T*)(s ? al0 : al1);
  const T* dtw = (const T*)(s ? dtw0 : dtw1);
  const T* dtb = (const T*)(s ? dtb0 : dtb1);
  const float* plane = ws + (s ? OFF_XC1 : OFF_XC0) + ((k & 1) ? 2 * DI * LSEQ : 0);
  int rev = (k >= 2);
  int l0 = c * CLEN;
  int mb = rev ? (4080 - l0) : l0;
  for (int i = d; i < 2048; i += 128) {
    int d2 = i >> 4, c2 = i & 15;
    us[d2 * 17 + c2] = plane[d2 * LSEQ + mb + c2];  // coalesced
  }
  if (d < 64) dtr[(d >> 4) * 16 + (d & 15)] = xd_dt[(d >> 4) * LSEQ + l0 + (d & 15)];
#pragma unroll
  for (int q = 0; q < 2; q++) {
    int i = d + q * 128;
    int n = i >> 4, j = i & 15;
    Bt[j * 20 + n] = Bb[n * LSEQ + l0 + j];
  }
  float A[NSTATE];
#pragma unroll
  for (int n = 0; n < NSTATE; n++) A[n] = -__expf(cvt(alog[(k * DI + d) * NSTATE + n]));
  bool fastp = true;
#pragma unroll
  for (int n = 1; n < NSTATE; n++)
    fastp = fastp && (fabsf(A[n] - (float)(n + 1) * A[0]) <= 1e-3f * fabsf(A[n]));
  float w0 = cvt(dtw[(k * DI + d) * 4 + 0]), w1 = cvt(dtw[(k * DI + d) * 4 + 1]);
  float w2 = cvt(dtw[(k * DI + d) * 4 + 2]), w3 = cvt(dtw[(k * DI + d) * 4 + 3]);
  float dbias = cvt(dtb[k * DI + d]);
  float h[NSTATE];
#pragma unroll
  for (int n = 0; n < NSTATE; n++) h[n] = 0.f;
  float sde = 0.f;
  __syncthreads();
  float de[16];
#pragma unroll
  for (int j = 0; j < 16; j++) {
    de[j] = softplus_f(dtr[j] * w0 + dtr[16 + j] * w1 + dtr[32 + j] * w2 + dtr[48 + j] * w3 +
                       dbias);
    sde += de[j];
  }
#pragma unroll
  for (int j = 0; j < 16; j++) {
    float u = us[d * 17 + (rev ? 15 - j : j)];
    float duj = de[j] * u;
    float4 b0 = *(const float4*)&Bt[j * 20 + 0];
    float4 b1 = *(const float4*)&Bt[j * 20 + 4];
    float4 b2 = *(const float4*)&Bt[j * 20 + 8];
    float4 b3 = *(const float4*)&Bt[j * 20 + 12];
    float bv[16] = {b0.x, b0.y, b0.z, b0.w, b1.x, b1.y, b1.z, b1.w,
                    b2.x, b2.y, b2.z, b2.w, b3.x, b3.y, b3.z, b3.w};
    if (fastp) {
      float e1 = __expf(de[j] * A[0]);
      float p = e1;
#pragma unroll
      for (int n = 0; n < NSTATE; n++) {
        h[n] = p * h[n] + duj * bv[n];
        p *= e1;
      }
    } else {
#pragma unroll
      for (int n = 0; n < NSTATE; n++) {
        float da = __expf(de[j] * A[n]);
        h[n] = da * h[n] + duj * bv[n];
      }
    }
  }
  int chainb = ((s * 4 + k) * DI + d) * NSTATE;
  float* Pp = ws + OFF_CHP + c * CHTOT + chainb;
  float* Sp = ws + OFF_CHS + c * CHTOT + chainb;
#pragma unroll
  for (int q = 0; q < 4; q++) {
    ((float4*)Pp)[q] = make_float4(__expf(A[4 * q] * sde), __expf(A[4 * q + 1] * sde),
                                   __expf(A[4 * q + 2] * sde), __expf(A[4 * q + 3] * sde));
    ((float4*)Sp)[q] = make_float4(h[4 * q], h[4 * q + 1], h[4 * q + 2], h[4 * q + 3]);
  }
}

template <typename T>
__device__ __forceinline__ void ph_scanB(const void* al0, const void* al1, const void* dtw0,
                                         const void* dtw1, const void* dtb0, const void* dtb1,
                                         const void* ds0, const void* ds1,
                                         float* __restrict__ ws, float* sm, int t, int gc) {
  int half = t >> 7, d = t & 127;
  int s = gc >> 10, k = (gc >> 8) & 3, c = gc & 255;
  float* base = sm + half * SB_HALF;
  float* us = base;
  float* dtr = base + 2176;
  float* Bt = base + 2240;
  float* Ct = base + 2560;
  const float* xd_dt = ws + OFF_XDBL + k * 36 * LSEQ;
  const float* Bb = xd_dt + 4 * LSEQ;
  const float* Cb = xd_dt + 20 * LSEQ;
  const T* alog = (const T*)(s ? al0 : al1);
  const T* dtw = (const T*)(s ? dtw0 : dtw1);
  const T* dtb = (const T*)(s ? dtb0 : dtb1);
  const T* Dvec = (const T*)(s ? ds0 : ds1);
  const float* plane = ws + (s ? OFF_XC1 : OFF_XC0) + ((k & 1) ? 2 * DI * LSEQ : 0);
  float* oyb = ws + OFF_OY + (s * NK + k) * (LSEQ * DI);
  int rev = (k >= 2);
  int l0 = c * CLEN;
  int mb = rev ? (4080 - l0) : l0;
  for (int i = d; i < 2048; i += 128) {
    int d2 = i >> 4, c2 = i & 15;
    us[d2 * 17 + c2] = plane[d2 * LSEQ + mb + c2];
  }
  if (d < 64) dtr[(d >> 4) * 16 + (d & 15)] = xd_dt[(d >> 4) * LSEQ + l0 + (d & 15)];
#pragma unroll
  for (int q = 0; q < 2; q++) {
    int i = d + q * 128;
    int n = i >> 4, j = i & 15;
    Bt[j * 20 + n] = Bb[n * LSEQ + l0 + j];
    Ct[j * 20 + n] = Cb[n * LSEQ + l0 + j];
  }
  float A[NSTATE];
#pragma unroll
  for (int n = 0; n < NSTATE; n++) A[n] = -__expf(cvt(alog[(k * DI + d) * NSTATE + n]));
  bool fastp = true;
#pragma unroll
  for (int n = 1; n < NSTATE; n++)
    fastp = fastp && (fabsf(A[n] - (float)(n + 1) * A[0]) <= 1e-3f * fabsf(A[n]));
  float w0 = cvt(dtw[(k * DI + d) * 4 + 0]), w1 = cvt(dtw[(k * DI + d) * 4 + 1]);
  float w2 = cvt(dtw[(k * DI + d) * 4 + 2]), w3 = cvt(dtw[(k * DI + d) * 4 + 3]);
  float dbias = cvt(dtb[k * DI + d]);
  float Dv = cvt(Dvec[k * DI + d]);
  int chainb = ((s * 4 + k) * DI + d) * NSTATE;
  const float* Hp = ws + OFF_CHP + c * CHTOT + chainb;
  float h[NSTATE];
#pragma unroll
  for (int q = 0; q < 4; q++) {
    float4 hv = ((const float4*)Hp)[q];
    h[4 * q] = hv.x; h[4 * q + 1] = hv.y; h[4 * q + 2] = hv.z; h[4 * q + 3] = hv.w;
  }
  __syncthreads();
  float de[16];
#pragma unroll
  for (int j = 0; j < 16; j++) {
    de[j] = softplus_f(dtr[j] * w0 + dtr[16 + j] * w1 + dtr[32 + j] * w2 + dtr[48 + j] * w3 +
                       dbias);
  }
#pragma unroll
  for (int j = 0; j < 16; j++) {
    float u = us[d * 17 + (rev ? 15 - j : j)];
    float duj = de[j] * u;
    float4 b0 = *(const float4*)&Bt[j * 20 + 0];
    float4 b1 = *(const float4*)&Bt[j * 20 + 4];
    float4 b2 = *(const float4*)&Bt[j * 20 + 8];
    float4 b3 = *(const float4*)&Bt[j * 20 + 12];
    float bv[16] = {b0.x, b0.y, b0.z, b0.w, b1.x, b1.y, b1.z, b1.w,
                    b2.x, b2.y, b2.z, b2.w, b3.x, b3.y, b3.z, b3.w};
    float4 c0 = *(const float4*)&Ct[j * 20 + 0];
    float4 c1 = *(const float4*)&Ct[j * 20 + 4];
    float4 c2 = *(const float4*)&Ct[j * 20 + 8];
    float4 c3 = *(const float4*)&Ct[j * 20 + 12];
    float cv[16] = {c0.x, c0.y, c0.z, c0.w, c1.x, c1.y, c1.z, c1.w,
                    c2.x, c2.y, c2.z, c2.w, c3.x, c3.y, c3.z, c3.w};
    float y = 0.f;
    if (fastp) {
      float e1 = __expf(de[j] * A[0]);
      float p = e1;
#pragma unroll
      for (int n = 0; n < NSTATE; n++) {
        h[n] = p * h[n] + duj * bv[n];
        y += h[n] * cv[n];
        p *= e1;
      }
    } else {
#pragma unroll
      for (int n = 0; n < NSTATE; n++) {
        float da = __expf(de[j] * A[n]);
        h[n] = da * h[n] + duj * bv[n];
        y += h[n] * cv[n];
      }
    }
    y += u * Dv;
    oyb[(l0 + j) * DI + d] = y;
  }
}

template <typename T>
__device__ __forceinline__ void ph_post(const void* g0_, const void* be0_, const void* g1_,
                                        const void* be1_, const void* wo0, const void* wo1,
                                        const float* __restrict__ ws, float* sm, int t,
                                        int unit, int f32, void* __restrict__ out) {
  int b = unit >> 8;
  int l0 = (unit & 255) * 16;
  const float* oy = ws + OFF_OY + b * (NK * LSEQ * DI);
  const float* sz = ws + (b ? OFF_SZ1 : OFF_SZ0);
  const T* g = (const T*)(b ? g1_ : g0_);
  const T* be = (const T*)(b ? be1_ : be0_);
  const T* wo = (const T*)(b ? wo1 : wo0);
  float* yl = sm;         // [16][132]
  float* wl = sm + 2112;  // [64][129]
  for (int i = t; i < 8192; i += 256) wl[(i >> 7) * 129 + (i & 127)] = cvt(wo[i]);
  int wv = t >> 6, lane = t & 63;
  float g1 = cvt(g[lane]), g2 = cvt(g[lane + 64]);
  float be1 = cvt(be[lane]), be2 = cvt(be[lane + 64]);
#pragma unroll
  for (int i = 0; i < 4; i++) {
    int r = wv + 4 * i;
    int l = l0 + r;
    int lt = ((l & 63) << 6) | (l >> 6);
    float v1 = oy[(0 * LSEQ + l) * DI + lane] + oy[(1 * LSEQ + lt) * DI + lane] +
               oy[(2 * LSEQ + (4095 - l)) * DI + lane] +
               oy[(3 * LSEQ + (4095 - lt)) * DI + lane];
    float v2 = oy[(0 * LSEQ + l) * DI + lane + 64] + oy[(1 * LSEQ + lt) * DI + lane + 64] +
               oy[(2 * LSEQ + (4095 - l)) * DI + lane + 64] +
               oy[(3 * LSEQ + (4095 - lt)) * DI + lane + 64];
    float s1 = v1 + v2, s2 = v1 * v1 + v2 * v2;
#pragma unroll
    for (int m = 1; m < 64; m <<= 1) {
      s1 += __shfl_xor(s1, m);
      s2 += __shfl_xor(s2, m);
    }
    float mean = s1 * (1.f / 128.f);
    float var = s2 * (1.f / 128.f) - mean * mean;
    float inv = rsqrtf(var + 1e-5f);
    yl[r * 132 + lane] = ((v1 - mean) * inv * g1 + be1) * sz[l * 128 + lane];
    yl[r * 132 + lane + 64] = ((v2 - mean) * inv * g2 + be2) * sz[l * 128 + lane + 64];
  }
  __syncthreads();
  int m = t & 63, rg = t >> 6;
  float acc0 = 0.f, acc1 = 0.f, acc2 = 0.f, acc3 = 0.f;
  for (int q = 0; q < 32; q++) {
    float w0 = wl[m * 129 + 4 * q], w1 = wl[m * 129 + 4 * q + 1];
    float w2 = wl[m * 129 + 4 * q + 2], w3 = wl[m * 129 + 4 * q + 3];
    float4 y0 = *(const float4*)&yl[(rg + 0) * 132 + 4 * q];
    float4 y1 = *(const float4*)&yl[(rg + 4) * 132 + 4 * q];
    float4 y2 = *(const float4*)&yl[(rg + 8) * 132 + 4 * q];
    float4 y3 = *(const float4*)&yl[(rg + 12) * 132 + 4 * q];
    acc0 += y0.x * w0 + y0.y * w1 + y0.z * w2 + y0.w * w3;
    acc1 += y1.x * w0 + y1.y * w1 + y1.z * w2 + y1.w * w3;
    acc2 += y2.x * w0 + y2.y * w1 + y2.z * w2 + y2.w * w3;
    acc3 += y3.x * w0 + y3.y * w1 + y3.z * w2 + y3.w * w3;
  }
  float accs[4] = {acc0, acc1, acc2, acc3};
#pragma unroll
  for (int i = 0; i < 4; i++) {
    int l = l0 + rg + 4 * i;
    int oi = b * (LSEQ * 64) + l * 64 + m;
    if (f32) ((float*)out)[oi] = accs[i];
    else ((bf16*)out)[oi] = __float2bfloat16(accs[i]);
  }
}

// ================= kernels: one wave-uniform dtype branch each =================

__global__ __launch_bounds__(256) void k_inproj(const void* x0, const void* x1,
                                                const void* w0, const void* w1,
                                                const void* probe, float* __restrict__ ws) {
  __shared__ __align__(16) float sm[2176];
  __shared__ int sf32;
  int t = threadIdx.x;
  int f32 = probe_f32(probe, t, &sf32);
  if (f32) ph_inproj<float>(x0, x1, w0, w1, ws, sm, t, blockIdx.x);
  else ph_inproj<bf16>(x0, x1, w0, w1, ws, sm, t, blockIdx.x);
}

__global__ __launch_bounds__(256) void k_conv(const void* cw0, const void* cb0,
                                              const void* cw1, const void* cb1,
                                              const void* probe, float* __restrict__ ws) {
  __shared__ __align__(16) float sm[8256];
  __shared__ int sf32;
  int t = threadIdx.x;
  int f32 = probe_f32(probe, t, &sf32);
  if (f32) ph_conv<float>(cw0, cb0, cw1, cb1, ws, sm, t, blockIdx.x);
  else ph_conv<bf16>(cw0, cb0, cw1, cb1, ws, sm, t, blockIdx.x);
}

__global__ __launch_bounds__(256) void k_xdbl(const void* xpw0, const void* probe,
                                              float* __restrict__ ws) {
  __shared__ __align__(16) float sm[8448 + 4608];
  __shared__ int sf32;
  int t = threadIdx.x;
  int f32 = probe_f32(probe, t, &sf32);
  if (f32) ph_xdbl<float>(xpw0, ws, sm, t, blockIdx.x);
  else ph_xdbl<bf16>(xpw0, ws, sm, t, blockIdx.x);
}

__global__ __launch_bounds__(256, 2) void k_scanA(const void* al0, const void* al1,
                                                  const void* dtw0, const void* dtw1,
                                                  const void* dtb0, const void* dtb1,
                                                  const void* probe, float* __restrict__ ws) {
  __shared__ __align__(16) float sm[2 * SA_HALF];
  __shared__ int sf32;
  int t = threadIdx.x;
  int f32 = probe_f32(probe, t, &sf32);
  int gc = blockIdx.x * 2 + (t >> 7);
  if (f32) ph_scanA<float>(al0, al1, dtw0, dtw1, dtb0, dtb1, ws, sm, t, gc);
  else ph_scanA<bf16>(al0, al1, dtw0, dtw1, dtb0, dtb1, ws, sm, t, gc);
}

__global__ __launch_bounds__(256) void k_comb(float* __restrict__ ws) {
  int chain = blockIdx.x * 256 + threadIdx.x;
  float* P = ws + OFF_CHP + chain;
  float* S = ws + OFF_CHS + chain;
  float h = 0.f;
  for (int g = 0; g < NCHUNK; g += 8) {
    float p[8], sv[8];
#pragma unroll
    for (int i = 0; i < 8; i++) {
      p[i] = P[(g + i) * CHTOT];
      sv[i] = S[(g + i) * CHTOT];
    }
#pragma unroll
    for (int i = 0; i < 8; i++) {
      P[(g + i) * CHTOT] = h;
      h = p[i] * h + sv[i];
    }
  }
}

__global__ __launch_bounds__(256, 2) void k_scanB(const void* al0, const void* al1,
                                                  const void* dtw0, const void* dtw1,
                                                  const void* dtb0, const void* dtb1,
                                                  const void* ds0, const void* ds1,
                                                  const void* probe, float* __restrict__ ws) {
  __shared__ __align__(16) float sm[2 * SB_HALF];
  __shared__ int sf32;
  int t = threadIdx.x;
  int f32 = probe_f32(probe, t, &sf32);
  int gc = blockIdx.x * 2 + (t >> 7);
  if (f32) ph_scanB<float>(al0, al1, dtw0, dtw1, dtb0, dtb1, ds0, ds1, ws, sm, t, gc);
  else ph_scanB<bf16>(al0, al1, dtw0, dtw1, dtb0, dtb1, ds0, ds1, ws, sm, t, gc);
}

__global__ __launch_bounds__(256) void k_post(const void* g0_, const void* be0_,
                                              const void* g1_, const void* be1_,
                                              const void* wo0, const void* wo1,
                                              const void* probe,
                                              const float* __restrict__ ws,
                                              void* __restrict__ out) {
  __shared__ __align__(16) float sm[10368];
  __shared__ int sf32;
  int t = threadIdx.x;
  int f32 = probe_f32(probe, t, &sf32);
  if (f32) ph_post<float>(g0_, be0_, g1_, be1_, wo0, wo1, ws, sm, t, blockIdx.x, f32, out);
  else ph_post<bf16>(g0_, be0_, g1_, be1_, wo0, wo1, ws, sm, t, blockIdx.x, f32, out);
}

extern "C" void kernel_launch(void* const* d_in, const int* in_sizes, int n_in,
                              void* d_out, int out_size, void* d_ws, size_t ws_size,
                              hipStream_t stream) {
  float* ws = (float*)d_ws;
  const void* probe = d_in[2];  // in_proj0_w

  k_inproj<<<dim3(512), 256, 0, stream>>>(d_in[0], d_in[1], d_in[2], d_in[3], probe, ws);
  k_conv<<<dim3(256), 256, 0, stream>>>(d_in[4], d_in[5], d_in[6], d_in[7], probe, ws);
  k_xdbl<<<dim3(256), 256, 0, stream>>>(d_in[8], probe, ws);
  k_scanA<<<dim3(1024), 256, 0, stream>>>(d_in[14], d_in[15], d_in[10], d_in[11],
                                          d_in[12], d_in[13], probe, ws);
  k_comb<<<dim3(64), 256, 0, stream>>>(ws);
  k_scanB<<<dim3(1024), 256, 0, stream>>>(d_in[14], d_in[15], d_in[10], d_in[11],
                                          d_in[12], d_in[13], d_in[16], d_in[17],
                                          probe, ws);
  k_post<<<dim3(512), 256, 0, stream>>>(d_in[18], d_in[19], d_in[20], d_in[21],
                                        d_in[22], d_in[23], probe, ws, d_out);
}